// Round 20
// baseline (177.447 us; speedup 1.0000x reference)
//
#include <hip/hip_runtime.h>
#include <math.h>

#define DIMX 384
#define SEQL 2048
#define NBATCH 2
#define DINNER 768
#define NSTATE 16
#define DTRANK 24
#define NTOK (NBATCH*SEQL)
#define NCHUNK 128
#define CHUNK (SEQL/NCHUNK)   // 16
#define NCH (2*NBATCH*DINNER) // 3072 channels (dir,b,d)
#define KSPL 4                // xproj K-split
#define KS (DINNER/KSPL)      // 192
#define CHSTR 20              // LDS row stride (ushorts) per chunk (16 data + 4 pad, 40B)
#define BCPD 65536            // BCP elements per db: 16 tb x 128 c x 32 packed (bf16)
#define LOG2E 1.44269504088896340736f

// bf16 weight pool offsets (elements)
#define WOFF_LIN 0
#define WOFF_W2  147456                    // 384*384
#define WOFF_XPW 737280                    // +1536*384
#define WOFF_WO  780288                    // +56*768
#define WTOTAL   1075200                   // +384*768
#define CVT_TOTAL (WTOTAL + NTOK*DIMX)     // weights + X

typedef __attribute__((ext_vector_type(8))) short bf16x8;
typedef __attribute__((ext_vector_type(8))) unsigned short u16x8;
typedef __attribute__((ext_vector_type(4))) float f32x4;
typedef __attribute__((ext_vector_type(2))) float f32x2;

__device__ __forceinline__ float silu_f(float x) {
  return x / (1.f + __expf(-x));
}

__device__ __forceinline__ unsigned short f2bf(float f) {
  unsigned int u = __float_as_uint(f);
  unsigned int r = u + 0x7fffu + ((u >> 16) & 1u);   // round-to-nearest-even
  return (unsigned short)(r >> 16);
}

__device__ __forceinline__ float bf2f(unsigned short u) {
  return __uint_as_float(((unsigned int)u) << 16);
}

// ---------------- pre-convert: weights + X fp32 -> bf16 (once per launch) ----------------
__global__ __launch_bounds__(256) void k_wcvt(const float* __restrict__ LINW,
    const float* __restrict__ W2, const float* __restrict__ XPW,
    const float* __restrict__ WO, const float* __restrict__ X,
    unsigned short* __restrict__ WB, unsigned short* __restrict__ XB) {
  const int e = (blockIdx.x * 256 + threadIdx.x) * 8;
  if (e >= CVT_TOTAL) return;
  const float* src;
  unsigned short* dst;
  int off;
  if (e < WOFF_W2)       { src = LINW; off = e - WOFF_LIN; dst = WB + e; }
  else if (e < WOFF_XPW) { src = W2;   off = e - WOFF_W2;  dst = WB + e; }
  else if (e < WOFF_WO)  { src = XPW;  off = e - WOFF_XPW; dst = WB + e; }
  else if (e < WTOTAL)   { src = WO;   off = e - WOFF_WO;  dst = WB + e; }
  else                   { src = X;    off = e - WTOTAL;   dst = XB + off; }
  float4 a = *(const float4*)&src[off];
  float4 b = *(const float4*)&src[off + 4];
  u16x8 v;
  v[0]=f2bf(a.x); v[1]=f2bf(a.y); v[2]=f2bf(a.z); v[3]=f2bf(a.w);
  v[4]=f2bf(b.x); v[5]=f2bf(b.y); v[6]=f2bf(b.z); v[7]=f2bf(b.w);
  *(u16x8*)dst = v;
}

// ---------------- GEMM1 (bf16 MFMA): Hb (bf16) = XB @ W^T + bias ----------------
__global__ __launch_bounds__(256) void k_lin(const unsigned short* __restrict__ XB,
    const unsigned short* __restrict__ WB, const float* __restrict__ bias,
    unsigned short* __restrict__ Hb) {
  __shared__ unsigned short LA[64][40];
  __shared__ unsigned short LB[64][40];
  const unsigned short* W = WB + WOFF_LIN;
  const int m0 = blockIdx.x * 64, n0 = blockIdx.y * 64;
  const int tid = threadIdx.x, lane = tid & 63, w = tid >> 6;
  const int wm = (w >> 1) * 32, wn = (w & 1) * 32;
  const int fr = lane & 15, fg = lane >> 4;
  const int srow = tid >> 2, skg = (tid & 3) * 8;
  f32x4 acc[2][2] = {};
  for (int k0 = 0; k0 < DIMX; k0 += 32) {
    u16x8 va = *(const u16x8*)&XB[(size_t)(m0 + srow) * DIMX + k0 + skg];
    u16x8 vb = *(const u16x8*)&W[(size_t)(n0 + srow) * DIMX + k0 + skg];
    *(u16x8*)&LA[srow][skg] = va;
    *(u16x8*)&LB[srow][skg] = vb;
    __syncthreads();
    bf16x8 af[2], bfr[2];
    af[0]  = *(const bf16x8*)&LA[wm + fr][fg*8];
    af[1]  = *(const bf16x8*)&LA[wm + 16 + fr][fg*8];
    bfr[0] = *(const bf16x8*)&LB[wn + fr][fg*8];
    bfr[1] = *(const bf16x8*)&LB[wn + 16 + fr][fg*8];
#pragma unroll
    for (int i = 0; i < 2; ++i)
#pragma unroll
      for (int j = 0; j < 2; ++j)
        acc[i][j] = __builtin_amdgcn_mfma_f32_16x16x32_bf16(af[i], bfr[j], acc[i][j], 0, 0, 0);
    __syncthreads();
  }
#pragma unroll
  for (int i = 0; i < 2; ++i)
#pragma unroll
    for (int j = 0; j < 2; ++j)
#pragma unroll
      for (int r = 0; r < 4; ++r) {
        int m = m0 + wm + i*16 + fg*4 + r;
        int n = n0 + wn + j*16 + fr;
        Hb[(size_t)m * DIMX + n] = f2bf(acc[i][j][r] + bias[n]);
      }
}

// ---------------- LayerNorm + ReLU: Hb (bf16) -> H2 (bf16) ----------------
__global__ __launch_bounds__(128) void k_ln(const unsigned short* __restrict__ Hb,
    const float* __restrict__ g, const float* __restrict__ bt,
    unsigned short* __restrict__ H2) {
  const int tok = blockIdx.x;
  const unsigned short* row = Hb + (size_t)tok * DIMX;
  unsigned short* orow = H2 + (size_t)tok * DIMX;
  const int tid = threadIdx.x;
  float v[3]; float s = 0.f, ss = 0.f;
#pragma unroll
  for (int i = 0; i < 3; ++i) { v[i] = bf2f(row[tid + i*128]); s += v[i]; ss += v[i]*v[i]; }
  for (int o = 32; o; o >>= 1) { s += __shfl_down(s, o); ss += __shfl_down(ss, o); }
  __shared__ float red[4];
  if ((tid & 63) == 0) { red[(tid>>6)*2] = s; red[(tid>>6)*2+1] = ss; }
  __syncthreads();
  float S = red[0] + red[2], SS = red[1] + red[3];
  float mu = S / DIMX;
  float var = SS / DIMX - mu * mu;
  float inv = rsqrtf(var + 1e-5f);
#pragma unroll
  for (int i = 0; i < 3; ++i) {
    int j = tid + i*128;
    float t = (v[i] - mu) * inv * g[j] + bt[j];
    orow[j] = f2bf(t > 0.f ? t : 0.f);
  }
}

// ---------------- GEMM2 (bf16 MFMA, 128x64 tile): x-channels -> XZ; z-channels -> silu -> ZS ----------------
__global__ __launch_bounds__(256) void k_inproj(const unsigned short* __restrict__ H2,
    const unsigned short* __restrict__ WB, unsigned short* __restrict__ XZ,
    unsigned short* __restrict__ ZS) {
  __shared__ unsigned short LA[128][40];  // [c][k]
  __shared__ unsigned short LB[64][40];   // [tok][k]
  const unsigned short* W2 = WB + WOFF_W2;
  const int n0 = blockIdx.x * 64;         // token tile
  const int m0 = blockIdx.y * 128;        // channel tile
  const int tid = threadIdx.x, lane = tid & 63, w = tid >> 6;
  const int wm = w * 32;                  // wave channel strip
  const int fr = lane & 15, fg = lane >> 4;
  const int srow = tid >> 2, skg = (tid & 3) * 8;
  f32x4 acc[2][4] = {};
  for (int k0 = 0; k0 < DIMX; k0 += 32) {
    u16x8 va0 = *(const u16x8*)&W2[(size_t)(m0 + srow) * DIMX + k0 + skg];
    u16x8 va1 = *(const u16x8*)&W2[(size_t)(m0 + 64 + srow) * DIMX + k0 + skg];
    u16x8 vb  = *(const u16x8*)&H2[(size_t)(n0 + srow) * DIMX + k0 + skg];
    *(u16x8*)&LA[srow][skg] = va0;
    *(u16x8*)&LA[srow + 64][skg] = va1;
    *(u16x8*)&LB[srow][skg] = vb;
    __syncthreads();
    bf16x8 af[2], bfr[4];
    af[0] = *(const bf16x8*)&LA[wm + fr][fg*8];
    af[1] = *(const bf16x8*)&LA[wm + 16 + fr][fg*8];
#pragma unroll
    for (int j = 0; j < 4; ++j)
      bfr[j] = *(const bf16x8*)&LB[j*16 + fr][fg*8];
#pragma unroll
    for (int i = 0; i < 2; ++i)
#pragma unroll
      for (int j = 0; j < 4; ++j)
        acc[i][j] = __builtin_amdgcn_mfma_f32_16x16x32_bf16(af[i], bfr[j], acc[i][j], 0, 0, 0);
    __syncthreads();
  }
  const int b = n0 >> 11;
  const int lbase = n0 & (SEQL - 1);
#pragma unroll
  for (int i = 0; i < 2; ++i)
#pragma unroll
    for (int j = 0; j < 4; ++j)
#pragma unroll
      for (int r = 0; r < 4; ++r) {
        int c = m0 + wm + i*16 + fg*4 + r;
        int l = lbase + j*16 + fr;
        if (c < DINNER)
          XZ[((size_t)(b*(2*DINNER) + c)) * SEQL + l] = f2bf(acc[i][j][r]);
        else
          ZS[((size_t)(b*DINNER + (c - DINNER))) * SEQL + l] = f2bf(silu_f(acc[i][j][r]));
      }
}

// ---------------- causal depthwise conv + silu (x-half only; 8 t/thread, bf16 in/out) ----------------
__global__ __launch_bounds__(256) void k_conv(const unsigned short* __restrict__ XZ,
    const float* __restrict__ cw, const float* __restrict__ cb,
    unsigned short* __restrict__ XC) {
  const int gid = blockIdx.x * 256 + threadIdx.x;   // over NCH * SEQL/8
  const int t0 = (gid & (SEQL/8 - 1)) * 8;
  const int c = gid >> 8;
  const int d = c % DINNER;
  const int db = c / DINNER;        // dir*2 + b
  const int b = db & 1, dir = db >> 1;
  const unsigned short* row = XZ + (size_t)(b*(2*DINNER) + d) * SEQL;
  const float w0 = cw[d*4+0], w1 = cw[d*4+1], w2 = cw[d*4+2], w3 = cw[d*4+3];
  const float cbd = cb[d];
  float win[11];
  if (dir == 0) {
    if (t0 >= 8) {
      u16x8 pv = *(const u16x8*)&row[t0 - 8];
      win[0] = bf2f(pv[5]); win[1] = bf2f(pv[6]); win[2] = bf2f(pv[7]);
    } else { win[0] = win[1] = win[2] = 0.f; }
    u16x8 cv = *(const u16x8*)&row[t0];
#pragma unroll
    for (int j = 0; j < 8; ++j) win[3 + j] = bf2f(cv[j]);
  } else {
    u16x8 cv = *(const u16x8*)&row[SEQL - 8 - t0];
#pragma unroll
    for (int j = 0; j < 8; ++j) win[j] = bf2f(cv[j]);
    if (t0 >= 8) {
      u16x8 nv = *(const u16x8*)&row[SEQL - t0];
      win[8] = bf2f(nv[0]); win[9] = bf2f(nv[1]); win[10] = bf2f(nv[2]);
    } else { win[8] = win[9] = win[10] = 0.f; }
  }
  u16x8 outv;
  if (dir == 0) {
#pragma unroll
    for (int i = 0; i < 8; ++i) {
      float s = cbd;
      s = fmaf(w0, win[i], s); s = fmaf(w1, win[i+1], s);
      s = fmaf(w2, win[i+2], s); s = fmaf(w3, win[i+3], s);
      outv[i] = f2bf(silu_f(s));
    }
  } else {
#pragma unroll
    for (int i = 0; i < 8; ++i) {
      float s = cbd;
      s = fmaf(w3, win[7-i], s); s = fmaf(w2, win[8-i], s);
      s = fmaf(w1, win[9-i], s); s = fmaf(w0, win[10-i], s);
      outv[i] = f2bf(silu_f(s));
    }
  }
  *(u16x8*)&XC[(size_t)(db * DINNER + d) * SEQL + t0] = outv;
}

// ---------------- x_proj (bf16 MFMA, split-K): PART[ks][db][n][t] ----------------
__global__ __launch_bounds__(256) void k_xproj(const unsigned short* __restrict__ XC,
    const unsigned short* __restrict__ WB, float* __restrict__ PART) {
  __shared__ unsigned short LA[64][40];   // [tok][k]
  __shared__ unsigned short LB[64][40];   // [n][k]; rows 56..63 unused
  __shared__ float OT[56][68];            // output stage [n][tok]
  const unsigned short* XPW = WB + WOFF_XPW;
  const int t0 = blockIdx.x * 64;
  const int ks = blockIdx.y;
  const int db = blockIdx.z;
  const int tid = threadIdx.x, lane = tid & 63, w = tid >> 6;
  const int wm = (w >> 1) * 32, wn = (w & 1) * 32;
  const int fr = lane & 15, fg = lane >> 4;
  const unsigned short* xc = XC + (size_t)db * DINNER * SEQL;
  const int kk = tid >> 3, tg = (tid & 7) * 8;   // A staging: 32 k x 8 tok-groups
  f32x4 acc[2][2] = {};
  const int kbase = ks * KS;
  for (int k0 = kbase; k0 < kbase + KS; k0 += 32) {
    u16x8 a = *(const u16x8*)&xc[(size_t)(k0 + kk) * SEQL + t0 + tg];
#pragma unroll
    for (int i = 0; i < 8; ++i) LA[tg + i][kk] = a[i];
#pragma unroll
    for (int i = 0; i < 7; ++i) {
      int e = tid + i * 256;        // < 1792 = 56*32
      int row = e >> 5, kc = e & 31;
      LB[row][kc] = XPW[(size_t)row * DINNER + k0 + kc];
    }
    __syncthreads();
    bf16x8 af[2], bfr[2];
    af[0]  = *(const bf16x8*)&LA[wm + fr][fg*8];
    af[1]  = *(const bf16x8*)&LA[wm + 16 + fr][fg*8];
    bfr[0] = *(const bf16x8*)&LB[wn + fr][fg*8];
    bfr[1] = *(const bf16x8*)&LB[wn + 16 + fr][fg*8];
#pragma unroll
    for (int i = 0; i < 2; ++i)
#pragma unroll
      for (int j = 0; j < 2; ++j)
        acc[i][j] = __builtin_amdgcn_mfma_f32_16x16x32_bf16(af[i], bfr[j], acc[i][j], 0, 0, 0);
    __syncthreads();
  }
#pragma unroll
  for (int i = 0; i < 2; ++i)
#pragma unroll
    for (int j = 0; j < 2; ++j)
#pragma unroll
      for (int r = 0; r < 4; ++r) {
        int n = wn + j*16 + fr;
        int tok = wm + i*16 + fg*4 + r;
        if (n < 56) OT[n][tok] = acc[i][j][r];
      }
  __syncthreads();
  for (int e = tid; e < 56 * 16; e += 256) {
    int row = e >> 4, c4 = e & 15;
    float4 v = *(const float4*)&OT[row][c4 * 4];
    *(float4*)&PART[((size_t)(ks*4 + db) * 56 + row) * SEQL + t0 + c4 * 4] = v;
  }
}

// ---------------- x_proj reduce: DTR (fp32) / BCP chunk-interleaved bf16 ----------------
// BCP[db][tb][c][p]: t = c*16+tb; state s: B at p=(s>>2)*8+(s&3), C at +4
__global__ __launch_bounds__(256) void k_xred(const float* __restrict__ PART,
    float* __restrict__ DTR, unsigned short* __restrict__ BCP) {
  const int idx = blockIdx.x * 256 + threadIdx.x;  // over 4*56*SEQL
  const int db = idx / (56 * SEQL);
  const int r  = idx % (56 * SEQL);
  const int n  = r / SEQL;
  const int t  = r % SEQL;
  float s = 0.f;
#pragma unroll
  for (int ks = 0; ks < KSPL; ++ks)
    s += PART[((size_t)(ks*4 + db) * 56 + n) * SEQL + t];
  if (n < DTRANK) {
    DTR[((size_t)db * DTRANK + n) * SEQL + t] = s;
  } else {
    int m = n - DTRANK;          // 0..31; B: m<16 (state m), C: m>=16 (state m-16)
    int st = (m < 16) ? m : (m - 16);
    int p = (st >> 2) * 8 + (st & 3) + ((m < 16) ? 0 : 4);
    int c = t >> 4, tb = t & 15;
    BCP[(size_t)db * BCPD + ((size_t)tb * 128 + c) * 32 + p] = f2bf(s);
  }
}

// ---------------- dt_proj + softplus -> delta (bf16) ----------------
__global__ __launch_bounds__(256) void k_dtproj(const float* __restrict__ DTR,
    const float* __restrict__ WDT, const float* __restrict__ BDT,
    unsigned short* __restrict__ DELTA) {
  __shared__ float S[DTRANK][256];
  const int t0 = blockIdx.x * 256;
  const int d0 = blockIdx.y * 8;
  const int db = blockIdx.z;  // dir*NBATCH + b
  const int tid = threadIdx.x;
  const float* src = DTR + (size_t)(db * DTRANK) * SEQL;
#pragma unroll
  for (int r = 0; r < DTRANK; ++r) S[r][tid] = src[(size_t)r * SEQL + t0 + tid];
  __syncthreads();
#pragma unroll
  for (int i = 0; i < 8; ++i) {
    int d = d0 + i;
    float s = BDT[d];
#pragma unroll
    for (int r = 0; r < DTRANK; ++r) s = fmaf(WDT[d*DTRANK + r], S[r][tid], s);
    float sp = fmaxf(s, 0.f) + log1pf(__expf(-fabsf(s)));
    DELTA[(size_t)(db * DINNER + d) * SEQL + t0 + tid] = f2bf(sp);
  }
}

// ---------------- fused selective scan: 128 chunks x 16 steps, 512 threads ----------------
// BCP bf16 chunk-interleaved (1KB/wave/step); A pre-scaled by log2(e); packed-f32 state math.
__global__ __launch_bounds__(512) void k_scanf(const unsigned short* __restrict__ DELTA,
    const unsigned short* __restrict__ XC, const unsigned short* __restrict__ BCP,
    const float* __restrict__ Alog, const float* __restrict__ Ablog,
    const float* __restrict__ Dp, unsigned short* __restrict__ Y) {
  __shared__ __align__(16) unsigned short sd[NCHUNK * CHSTR];  // delta (bf16)
  __shared__ __align__(16) unsigned short sx[NCHUNK * CHSTR];  // conv+silu x (bf16)
  __shared__ __align__(16) unsigned short sy[NCHUNK * CHSTR];  // ungated y staging
  __shared__ float sHL[NCHUNK][16];   // local h_end -> (in-place) h_start
  __shared__ float sDS[NCHUNK];
  const int tid = threadIdx.x;
  const int ch = blockIdx.x;          // 0..NCH-1
  const int db = ch / DINNER;         // dir*2 + b
  const int d  = ch % DINNER;
  const int dir = db >> 1;
  const unsigned short* gd = DELTA + (size_t)(db * DINNER + d) * SEQL;
  const unsigned short* gx = XC    + (size_t)(db * DINNER + d) * SEQL;
  const unsigned short* bcq = BCP + (size_t)db * BCPD;
  {
    int e = tid * 4;                  // 512 threads x 4 = 2048
    int r = e >> 4, cl = e & 15;
    *(ushort4*)&sd[r * CHSTR + cl] = *(const ushort4*)&gd[e];
    *(ushort4*)&sx[r * CHSTR + cl] = *(const ushort4*)&gx[e];
  }
  const int lk = tid & 3;            // state-quad lane
  const int cq = tid >> 2;           // chunk 0..127
  const float* Ap = (dir ? Ablog : Alog) + (size_t)d * NSTATE + 4 * lk;
  f32x2 Av01, Av23;                  // -exp(A_log) * log2(e), packed
  Av01.x = -__expf(Ap[0]) * LOG2E;  Av01.y = -__expf(Ap[1]) * LOG2E;
  Av23.x = -__expf(Ap[2]) * LOG2E;  Av23.y = -__expf(Ap[3]) * LOG2E;
  __syncthreads();
  // ---- pass 1: local scan, h0 = 0 (B-only ushort4 loads) ----
  {
    f32x2 h01 = {0.f, 0.f}, h23 = {0.f, 0.f};
    float dsum = 0.f;
#pragma unroll
    for (int tb4 = 0; tb4 < CHUNK; tb4 += 4) {
      const int base = cq * CHSTR + tb4;
      ushort4 dl4 = *(const ushort4*)&sd[base];   // quad-broadcast 8B
      ushort4 xl4 = *(const ushort4*)&sx[base];
      float dl[4] = {bf2f(dl4.x), bf2f(dl4.y), bf2f(dl4.z), bf2f(dl4.w)};
      float xl[4] = {bf2f(xl4.x), bf2f(xl4.y), bf2f(xl4.z), bf2f(xl4.w)};
      dsum += dl[0] + dl[1] + dl[2] + dl[3];
#pragma unroll
      for (int k = 0; k < 4; ++k) {
        float u = dl[k] * xl[k];
        ushort4 b4 = *(const ushort4*)&bcq[((size_t)(tb4 + k) * 128 + cq) * 32 + lk * 8];
        f32x2 dl2 = {dl[k], dl[k]};
        f32x2 t01 = dl2 * Av01, t23 = dl2 * Av23;
        f32x2 dA01, dA23;
        dA01.x = __builtin_amdgcn_exp2f(t01.x); dA01.y = __builtin_amdgcn_exp2f(t01.y);
        dA23.x = __builtin_amdgcn_exp2f(t23.x); dA23.y = __builtin_amdgcn_exp2f(t23.y);
        f32x2 u2 = {u, u};
        f32x2 b01 = {bf2f(b4.x), bf2f(b4.y)};
        f32x2 b23 = {bf2f(b4.z), bf2f(b4.w)};
        h01 = __builtin_elementwise_fma(dA01, h01, u2 * b01);
        h23 = __builtin_elementwise_fma(dA23, h23, u2 * b23);
      }
    }
    if (lk == 0) sDS[cq] = dsum;
    float4 hv = {h01.x, h01.y, h23.x, h23.y};
    *(float4*)&sHL[cq][4 * lk] = hv;
  }
  __syncthreads();
  // ---- fixup (in place): sHL[c] becomes h_start for chunk c ----
  if (tid < NSTATE) {
    const int n = tid;
    const float Aval = -__expf((dir ? Ablog : Alog)[(size_t)d * NSTATE + n]) * LOG2E;
    float hh = 0.f;
#pragma unroll 4
    for (int c2 = 0; c2 < NCHUNK; ++c2) {
      float tmp = sHL[c2][n];
      sHL[c2][n] = hh;
      hh = fmaf(__builtin_amdgcn_exp2f(sDS[c2] * Aval), hh, tmp);
    }
  }
  __syncthreads();
  // ---- pass 2: recompute with true h_start, emit UNGATED y into sy ----
  {
    const float Dd = Dp[d];
    float4 h0v = *(const float4*)&sHL[cq][4 * lk];
    f32x2 h01 = {h0v.x, h0v.y}, h23 = {h0v.z, h0v.w};
#pragma unroll
    for (int tb4 = 0; tb4 < CHUNK; tb4 += 4) {
      const int base = cq * CHSTR + tb4;
      ushort4 dl4 = *(const ushort4*)&sd[base];
      ushort4 xl4 = *(const ushort4*)&sx[base];
      float dl[4] = {bf2f(dl4.x), bf2f(dl4.y), bf2f(dl4.z), bf2f(dl4.w)};
      float xl[4] = {bf2f(xl4.x), bf2f(xl4.y), bf2f(xl4.z), bf2f(xl4.w)};
      float pp[4];
#pragma unroll
      for (int k = 0; k < 4; ++k) {
        float u = dl[k] * xl[k];
        u16x8 v = *(const u16x8*)&bcq[((size_t)(tb4 + k) * 128 + cq) * 32 + lk * 8];
        f32x2 dl2 = {dl[k], dl[k]};
        f32x2 t01 = dl2 * Av01, t23 = dl2 * Av23;
        f32x2 dA01, dA23;
        dA01.x = __builtin_amdgcn_exp2f(t01.x); dA01.y = __builtin_amdgcn_exp2f(t01.y);
        dA23.x = __builtin_amdgcn_exp2f(t23.x); dA23.y = __builtin_amdgcn_exp2f(t23.y);
        f32x2 u2 = {u, u};
        f32x2 b01 = {bf2f(v[0]), bf2f(v[1])};
        f32x2 b23 = {bf2f(v[2]), bf2f(v[3])};
        f32x2 c01 = {bf2f(v[4]), bf2f(v[5])};
        f32x2 c23 = {bf2f(v[6]), bf2f(v[7])};
        h01 = __builtin_elementwise_fma(dA01, h01, u2 * b01);
        h23 = __builtin_elementwise_fma(dA23, h23, u2 * b23);
        f32x2 pyv = __builtin_elementwise_fma(h23, c23, h01 * c01);
        pp[k] = pyv.x + pyv.y;
      }
      const int i0 = lk & 1;
      float u0 = __shfl_xor(pp[i0 ^ 1], 1, 4);
      float u1 = __shfl_xor(pp[(i0 ^ 1) + 2], 1, 4);
      float s0 = pp[i0] + u0;
      float s1 = pp[i0 + 2] + u1;
      float send = (lk & 2) ? s0 : s1;
      float v2 = __shfl_xor(send, 2, 4);
      float keep = (lk & 2) ? s1 : s0;
      float ysum = keep + v2;
      float yv = fmaf(xl[lk], Dd, ysum);
      sy[base + lk] = f2bf(yv);
    }
  }
  __syncthreads();
  unsigned short* gy = Y + (size_t)(db * DINNER + d) * SEQL;
  {
    int e = tid * 4;
    int r = e >> 4, cl = e & 15;
    *(ushort4*)&gy[e] = *(const ushort4*)&sy[r * CHSTR + cl];
  }
}

// ---------------- out_proj (bf16 MFMA, 64x64 tile) + residual; gates y during staging ----------------
__global__ __launch_bounds__(256) void k_outproj(const unsigned short* __restrict__ Y,
    const unsigned short* __restrict__ ZS, const unsigned short* __restrict__ WB,
    const float* __restrict__ X, float* __restrict__ OUT) {
  __shared__ unsigned short LA[64][40];   // [tok][k] (transposed + gated stage)
  __shared__ unsigned short LB[64][40];   // [o][k]
  const unsigned short* WO = WB + WOFF_WO;
  const int m0 = blockIdx.x * 64;         // token tile
  const int n0 = blockIdx.y * 64;         // output-dim tile
  const int tid = threadIdx.x, lane = tid & 63, w = tid >> 6;
  const int wm = (w >> 1) * 32, wn = (w & 1) * 32;
  const int fr = lane & 15, fg = lane >> 4;
  const int b = m0 >> 11, lb = m0 & (SEQL - 1);
  const unsigned short* y0 = Y + (size_t)b * DINNER * SEQL;                 // fwd, natural
  const unsigned short* y1 = Y + (size_t)(NBATCH + b) * DINNER * SEQL;      // bwd, scan frame
  const unsigned short* zsb = ZS + (size_t)b * DINNER * SEQL;
  const int kk = tid >> 3, tg = (tid & 7) * 8;   // A staging: 32 k x 8 tok-groups
  const int srow = tid >> 2, skg = (tid & 3) * 8; // B staging
  f32x4 acc[2][2] = {};
  for (int k0 = 0; k0 < DINNER; k0 += 32) {
    const unsigned short* p0 = y0  + (size_t)(k0 + kk) * SEQL + lb + tg;
    const unsigned short* p1 = y1  + (size_t)(k0 + kk) * SEQL + (SEQL - 8 - lb - tg);
    const unsigned short* pz = zsb + (size_t)(k0 + kk) * SEQL + lb + tg;
    u16x8 a0 = *(const u16x8*)p0;
    u16x8 a1 = *(const u16x8*)p1;   // reversed block; element i corresponds to tok offset 7-i
    u16x8 az = *(const u16x8*)pz;
#pragma unroll
    for (int i = 0; i < 8; ++i)
      LA[tg + i][kk] = f2bf((bf2f(a0[i]) + bf2f(a1[7 - i])) * bf2f(az[i]));
    u16x8 vb = *(const u16x8*)&WO[(size_t)(n0 + srow) * DINNER + k0 + skg];
    *(u16x8*)&LB[srow][skg] = vb;
    __syncthreads();
    bf16x8 af[2], bfr[2];
    af[0]  = *(const bf16x8*)&LA[wm + fr][fg*8];
    af[1]  = *(const bf16x8*)&LA[wm + 16 + fr][fg*8];
    bfr[0] = *(const bf16x8*)&LB[wn + fr][fg*8];
    bfr[1] = *(const bf16x8*)&LB[wn + 16 + fr][fg*8];
#pragma unroll
    for (int i = 0; i < 2; ++i)
#pragma unroll
      for (int j = 0; j < 2; ++j)
        acc[i][j] = __builtin_amdgcn_mfma_f32_16x16x32_bf16(af[i], bfr[j], acc[i][j], 0, 0, 0);
    __syncthreads();
  }
#pragma unroll
  for (int i = 0; i < 2; ++i)
#pragma unroll
    for (int j = 0; j < 2; ++j)
#pragma unroll
      for (int r = 0; r < 4; ++r) {
        int tok = m0 + wm + i*16 + fg*4 + r;
        int o = n0 + wn + j*16 + fr;
        size_t off = (size_t)tok * DIMX + o;
        OUT[off] = acc[i][j][r] + X[off];
      }
}

extern "C" void kernel_launch(void* const* d_in, const int* in_sizes, int n_in,
                              void* d_out, int out_size, void* d_ws, size_t ws_size,
                              hipStream_t stream) {
  (void)in_sizes; (void)n_in; (void)out_size; (void)ws_size;
  const float* x         = (const float*)d_in[0];
  const float* lin_w     = (const float*)d_in[1];
  const float* lin_b     = (const float*)d_in[2];
  const float* ln_g      = (const float*)d_in[3];
  const float* ln_b      = (const float*)d_in[4];
  const float* in_proj_w = (const float*)d_in[5];
  const float* conv_w    = (const float*)d_in[6];
  const float* conv_b    = (const float*)d_in[7];
  const float* x_proj_w  = (const float*)d_in[8];
  const float* dt_proj_w = (const float*)d_in[9];
  const float* dt_proj_b = (const float*)d_in[10];
  const float* A_log     = (const float*)d_in[11];
  const float* A_b_log   = (const float*)d_in[12];
  const float* Dp        = (const float*)d_in[13];
  const float* out_proj_w= (const float*)d_in[14];
  float* out = (float*)d_out;

  float* ws = (float*)d_ws;
  unsigned short* hb = (unsigned short*)ws; ws += (size_t)NTOK * DIMX / 2;        // bf16 pre-LN H
  unsigned short* h2 = (unsigned short*)ws; ws += (size_t)NTOK * DIMX / 2;        // bf16 post-LN H
  unsigned short* xb = (unsigned short*)ws; ws += (size_t)NTOK * DIMX / 2;        // bf16 X
  unsigned short* xz = (unsigned short*)ws;  ws += (size_t)NBATCH * 2*DINNER * SEQL / 2; // bf16 (z half unused)
  unsigned short* xc  = (unsigned short*)ws;  ws += (size_t)NCH * SEQL / 2;       // bf16
  unsigned short* dlt = (unsigned short*)ws;  ws += (size_t)NCH * SEQL / 2;       // bf16
  unsigned short* zs  = (unsigned short*)ws;  ws += (size_t)NBATCH * DINNER * SEQL / 2; // bf16
  float* dtr  = ws;  ws += (size_t)2 * NBATCH * DTRANK * SEQL;
  unsigned short* bcp = (unsigned short*)ws;  ws += (size_t)4 * BCPD / 2;         // bf16 chunk-interleaved
  unsigned short* wbf = (unsigned short*)ws;  ws += (size_t)(WTOTAL + 512) / 2;   // bf16 weight pool
  float* y01f = ws;  ws += (size_t)NCH * SEQL / 2;            // bf16 Y (+ PART overlay)
  unsigned short* y01 = (unsigned short*)y01f;
  float* PART = y01f; // overlay: KSPL*4*56*SEQL fp32 (1.84M) <= region (3.14M floats); PART dead after k_xred

  k_wcvt<<<(CVT_TOTAL/8 + 255)/256, 256, 0, stream>>>(lin_w, in_proj_w, x_proj_w, out_proj_w, x, wbf, xb);
  k_lin<<<dim3(NTOK/64, DIMX/64), 256, 0, stream>>>(xb, wbf, lin_b, hb);
  k_ln<<<NTOK, 128, 0, stream>>>(hb, ln_g, ln_b, h2);
  k_inproj<<<dim3(NTOK/64, 2*DINNER/128), 256, 0, stream>>>(h2, wbf, xz, zs);
  k_conv<<<(NCH*(SEQL/8))/256, 256, 0, stream>>>(xz, conv_w, conv_b, xc);
  k_xproj<<<dim3(SEQL/64, KSPL, 2*NBATCH), 256, 0, stream>>>(xc, wbf, PART);
  k_xred<<<(2*NBATCH*56*SEQL)/256, 256, 0, stream>>>(PART, dtr, bcp);
  k_dtproj<<<dim3(SEQL/256, DINNER/8, 2*NBATCH), 256, 0, stream>>>(dtr, dt_proj_w, dt_proj_b, dlt);
  k_scanf<<<NCH, 512, 0, stream>>>(dlt, xc, bcp, A_log, A_b_log, Dp, y01);
  k_outproj<<<dim3(NTOK/64, DIMX/64), 256, 0, stream>>>(y01, zs, wbf, x, out);
}

// Round 21
// 159.134 us; speedup vs baseline: 1.1151x; 1.1151x over previous
//
#include <hip/hip_runtime.h>
#include <math.h>

#define DIMX 384
#define SEQL 2048
#define NBATCH 2
#define DINNER 768
#define NSTATE 16
#define DTRANK 24
#define NTOK (NBATCH*SEQL)
#define NCHUNK 64
#define CHUNK (SEQL/NCHUNK)   // 32
#define NCH (2*NBATCH*DINNER) // 3072 channels (dir,b,d)
#define KSPL 4                // xproj K-split
#define KS (DINNER/KSPL)      // 192
#define CHSTR 40              // LDS row stride (ushorts) per chunk (32 data + 8 pad, 80B)
#define BCPD 65536            // BCP elements per db: 32 tb x 64 c x 32 packed (bf16)
#define LOG2E 1.44269504088896340736f

// bf16 weight pool offsets (elements)
#define WOFF_LIN 0
#define WOFF_W2  147456                    // 384*384
#define WOFF_XPW 737280                    // +1536*384
#define WOFF_WO  780288                    // +56*768
#define WTOTAL   1075200                   // +384*768
#define CVT_TOTAL (WTOTAL + NTOK*DIMX)     // weights + X

typedef __attribute__((ext_vector_type(8))) short bf16x8;
typedef __attribute__((ext_vector_type(8))) unsigned short u16x8;
typedef __attribute__((ext_vector_type(4))) float f32x4;
typedef __attribute__((ext_vector_type(2))) float f32x2;

__device__ __forceinline__ float silu_f(float x) {
  return x / (1.f + __expf(-x));
}

__device__ __forceinline__ unsigned short f2bf(float f) {
  unsigned int u = __float_as_uint(f);
  unsigned int r = u + 0x7fffu + ((u >> 16) & 1u);   // round-to-nearest-even
  return (unsigned short)(r >> 16);
}

__device__ __forceinline__ float bf2f(unsigned short u) {
  return __uint_as_float(((unsigned int)u) << 16);
}

// ---------------- pre-convert: weights + X fp32 -> bf16 (once per launch) ----------------
__global__ __launch_bounds__(256) void k_wcvt(const float* __restrict__ LINW,
    const float* __restrict__ W2, const float* __restrict__ XPW,
    const float* __restrict__ WO, const float* __restrict__ X,
    unsigned short* __restrict__ WB, unsigned short* __restrict__ XB) {
  const int e = (blockIdx.x * 256 + threadIdx.x) * 8;
  if (e >= CVT_TOTAL) return;
  const float* src;
  unsigned short* dst;
  int off;
  if (e < WOFF_W2)       { src = LINW; off = e - WOFF_LIN; dst = WB + e; }
  else if (e < WOFF_XPW) { src = W2;   off = e - WOFF_W2;  dst = WB + e; }
  else if (e < WOFF_WO)  { src = XPW;  off = e - WOFF_XPW; dst = WB + e; }
  else if (e < WTOTAL)   { src = WO;   off = e - WOFF_WO;  dst = WB + e; }
  else                   { src = X;    off = e - WTOTAL;   dst = XB + off; }
  float4 a = *(const float4*)&src[off];
  float4 b = *(const float4*)&src[off + 4];
  u16x8 v;
  v[0]=f2bf(a.x); v[1]=f2bf(a.y); v[2]=f2bf(a.z); v[3]=f2bf(a.w);
  v[4]=f2bf(b.x); v[5]=f2bf(b.y); v[6]=f2bf(b.z); v[7]=f2bf(b.w);
  *(u16x8*)dst = v;
}

// ---------------- GEMM1 (bf16 MFMA): Hb (bf16) = XB @ W^T + bias ----------------
__global__ __launch_bounds__(256) void k_lin(const unsigned short* __restrict__ XB,
    const unsigned short* __restrict__ WB, const float* __restrict__ bias,
    unsigned short* __restrict__ Hb) {
  __shared__ unsigned short LA[64][40];
  __shared__ unsigned short LB[64][40];
  const unsigned short* W = WB + WOFF_LIN;
  const int m0 = blockIdx.x * 64, n0 = blockIdx.y * 64;
  const int tid = threadIdx.x, lane = tid & 63, w = tid >> 6;
  const int wm = (w >> 1) * 32, wn = (w & 1) * 32;
  const int fr = lane & 15, fg = lane >> 4;
  const int srow = tid >> 2, skg = (tid & 3) * 8;
  f32x4 acc[2][2] = {};
  for (int k0 = 0; k0 < DIMX; k0 += 32) {
    u16x8 va = *(const u16x8*)&XB[(size_t)(m0 + srow) * DIMX + k0 + skg];
    u16x8 vb = *(const u16x8*)&W[(size_t)(n0 + srow) * DIMX + k0 + skg];
    *(u16x8*)&LA[srow][skg] = va;
    *(u16x8*)&LB[srow][skg] = vb;
    __syncthreads();
    bf16x8 af[2], bfr[2];
    af[0]  = *(const bf16x8*)&LA[wm + fr][fg*8];
    af[1]  = *(const bf16x8*)&LA[wm + 16 + fr][fg*8];
    bfr[0] = *(const bf16x8*)&LB[wn + fr][fg*8];
    bfr[1] = *(const bf16x8*)&LB[wn + 16 + fr][fg*8];
#pragma unroll
    for (int i = 0; i < 2; ++i)
#pragma unroll
      for (int j = 0; j < 2; ++j)
        acc[i][j] = __builtin_amdgcn_mfma_f32_16x16x32_bf16(af[i], bfr[j], acc[i][j], 0, 0, 0);
    __syncthreads();
  }
#pragma unroll
  for (int i = 0; i < 2; ++i)
#pragma unroll
    for (int j = 0; j < 2; ++j)
#pragma unroll
      for (int r = 0; r < 4; ++r) {
        int m = m0 + wm + i*16 + fg*4 + r;
        int n = n0 + wn + j*16 + fr;
        Hb[(size_t)m * DIMX + n] = f2bf(acc[i][j][r] + bias[n]);
      }
}

// ---------------- LayerNorm + ReLU: Hb (bf16) -> H2 (bf16) ----------------
__global__ __launch_bounds__(128) void k_ln(const unsigned short* __restrict__ Hb,
    const float* __restrict__ g, const float* __restrict__ bt,
    unsigned short* __restrict__ H2) {
  const int tok = blockIdx.x;
  const unsigned short* row = Hb + (size_t)tok * DIMX;
  unsigned short* orow = H2 + (size_t)tok * DIMX;
  const int tid = threadIdx.x;
  float v[3]; float s = 0.f, ss = 0.f;
#pragma unroll
  for (int i = 0; i < 3; ++i) { v[i] = bf2f(row[tid + i*128]); s += v[i]; ss += v[i]*v[i]; }
  for (int o = 32; o; o >>= 1) { s += __shfl_down(s, o); ss += __shfl_down(ss, o); }
  __shared__ float red[4];
  if ((tid & 63) == 0) { red[(tid>>6)*2] = s; red[(tid>>6)*2+1] = ss; }
  __syncthreads();
  float S = red[0] + red[2], SS = red[1] + red[3];
  float mu = S / DIMX;
  float var = SS / DIMX - mu * mu;
  float inv = rsqrtf(var + 1e-5f);
#pragma unroll
  for (int i = 0; i < 3; ++i) {
    int j = tid + i*128;
    float t = (v[i] - mu) * inv * g[j] + bt[j];
    orow[j] = f2bf(t > 0.f ? t : 0.f);
  }
}

// ---------------- GEMM2 (bf16 MFMA, 128x64 tile): x-channels -> XZ; z-channels -> silu -> ZS ----------------
__global__ __launch_bounds__(256) void k_inproj(const unsigned short* __restrict__ H2,
    const unsigned short* __restrict__ WB, unsigned short* __restrict__ XZ,
    unsigned short* __restrict__ ZS) {
  __shared__ unsigned short LA[128][40];  // [c][k]
  __shared__ unsigned short LB[64][40];   // [tok][k]
  const unsigned short* W2 = WB + WOFF_W2;
  const int n0 = blockIdx.x * 64;         // token tile
  const int m0 = blockIdx.y * 128;        // channel tile
  const int tid = threadIdx.x, lane = tid & 63, w = tid >> 6;
  const int wm = w * 32;                  // wave channel strip
  const int fr = lane & 15, fg = lane >> 4;
  const int srow = tid >> 2, skg = (tid & 3) * 8;
  f32x4 acc[2][4] = {};
  for (int k0 = 0; k0 < DIMX; k0 += 32) {
    u16x8 va0 = *(const u16x8*)&W2[(size_t)(m0 + srow) * DIMX + k0 + skg];
    u16x8 va1 = *(const u16x8*)&W2[(size_t)(m0 + 64 + srow) * DIMX + k0 + skg];
    u16x8 vb  = *(const u16x8*)&H2[(size_t)(n0 + srow) * DIMX + k0 + skg];
    *(u16x8*)&LA[srow][skg] = va0;
    *(u16x8*)&LA[srow + 64][skg] = va1;
    *(u16x8*)&LB[srow][skg] = vb;
    __syncthreads();
    bf16x8 af[2], bfr[4];
    af[0] = *(const bf16x8*)&LA[wm + fr][fg*8];
    af[1] = *(const bf16x8*)&LA[wm + 16 + fr][fg*8];
#pragma unroll
    for (int j = 0; j < 4; ++j)
      bfr[j] = *(const bf16x8*)&LB[j*16 + fr][fg*8];
#pragma unroll
    for (int i = 0; i < 2; ++i)
#pragma unroll
      for (int j = 0; j < 4; ++j)
        acc[i][j] = __builtin_amdgcn_mfma_f32_16x16x32_bf16(af[i], bfr[j], acc[i][j], 0, 0, 0);
    __syncthreads();
  }
  const int b = n0 >> 11;
  const int lbase = n0 & (SEQL - 1);
#pragma unroll
  for (int i = 0; i < 2; ++i)
#pragma unroll
    for (int j = 0; j < 4; ++j)
#pragma unroll
      for (int r = 0; r < 4; ++r) {
        int c = m0 + wm + i*16 + fg*4 + r;
        int l = lbase + j*16 + fr;
        if (c < DINNER)
          XZ[((size_t)(b*(2*DINNER) + c)) * SEQL + l] = f2bf(acc[i][j][r]);
        else
          ZS[((size_t)(b*DINNER + (c - DINNER))) * SEQL + l] = f2bf(silu_f(acc[i][j][r]));
      }
}

// ---------------- causal depthwise conv + silu (x-half only; 8 t/thread, bf16 in/out) ----------------
__global__ __launch_bounds__(256) void k_conv(const unsigned short* __restrict__ XZ,
    const float* __restrict__ cw, const float* __restrict__ cb,
    unsigned short* __restrict__ XC) {
  const int gid = blockIdx.x * 256 + threadIdx.x;   // over NCH * SEQL/8
  const int t0 = (gid & (SEQL/8 - 1)) * 8;
  const int c = gid >> 8;
  const int d = c % DINNER;
  const int db = c / DINNER;        // dir*2 + b
  const int b = db & 1, dir = db >> 1;
  const unsigned short* row = XZ + (size_t)(b*(2*DINNER) + d) * SEQL;
  const float w0 = cw[d*4+0], w1 = cw[d*4+1], w2 = cw[d*4+2], w3 = cw[d*4+3];
  const float cbd = cb[d];
  float win[11];
  if (dir == 0) {
    if (t0 >= 8) {
      u16x8 pv = *(const u16x8*)&row[t0 - 8];
      win[0] = bf2f(pv[5]); win[1] = bf2f(pv[6]); win[2] = bf2f(pv[7]);
    } else { win[0] = win[1] = win[2] = 0.f; }
    u16x8 cv = *(const u16x8*)&row[t0];
#pragma unroll
    for (int j = 0; j < 8; ++j) win[3 + j] = bf2f(cv[j]);
  } else {
    u16x8 cv = *(const u16x8*)&row[SEQL - 8 - t0];
#pragma unroll
    for (int j = 0; j < 8; ++j) win[j] = bf2f(cv[j]);
    if (t0 >= 8) {
      u16x8 nv = *(const u16x8*)&row[SEQL - t0];
      win[8] = bf2f(nv[0]); win[9] = bf2f(nv[1]); win[10] = bf2f(nv[2]);
    } else { win[8] = win[9] = win[10] = 0.f; }
  }
  u16x8 outv;
  if (dir == 0) {
#pragma unroll
    for (int i = 0; i < 8; ++i) {
      float s = cbd;
      s = fmaf(w0, win[i], s); s = fmaf(w1, win[i+1], s);
      s = fmaf(w2, win[i+2], s); s = fmaf(w3, win[i+3], s);
      outv[i] = f2bf(silu_f(s));
    }
  } else {
#pragma unroll
    for (int i = 0; i < 8; ++i) {
      float s = cbd;
      s = fmaf(w3, win[7-i], s); s = fmaf(w2, win[8-i], s);
      s = fmaf(w1, win[9-i], s); s = fmaf(w0, win[10-i], s);
      outv[i] = f2bf(silu_f(s));
    }
  }
  *(u16x8*)&XC[(size_t)(db * DINNER + d) * SEQL + t0] = outv;
}

// ---------------- x_proj (bf16 MFMA, split-K): PART[ks][db][n][t] ----------------
__global__ __launch_bounds__(256) void k_xproj(const unsigned short* __restrict__ XC,
    const unsigned short* __restrict__ WB, float* __restrict__ PART) {
  __shared__ unsigned short LA[64][40];   // [tok][k]
  __shared__ unsigned short LB[64][40];   // [n][k]; rows 56..63 unused
  __shared__ float OT[56][68];            // output stage [n][tok]
  const unsigned short* XPW = WB + WOFF_XPW;
  const int t0 = blockIdx.x * 64;
  const int ks = blockIdx.y;
  const int db = blockIdx.z;
  const int tid = threadIdx.x, lane = tid & 63, w = tid >> 6;
  const int wm = (w >> 1) * 32, wn = (w & 1) * 32;
  const int fr = lane & 15, fg = lane >> 4;
  const unsigned short* xc = XC + (size_t)db * DINNER * SEQL;
  const int kk = tid >> 3, tg = (tid & 7) * 8;   // A staging: 32 k x 8 tok-groups
  f32x4 acc[2][2] = {};
  const int kbase = ks * KS;
  for (int k0 = kbase; k0 < kbase + KS; k0 += 32) {
    u16x8 a = *(const u16x8*)&xc[(size_t)(k0 + kk) * SEQL + t0 + tg];
#pragma unroll
    for (int i = 0; i < 8; ++i) LA[tg + i][kk] = a[i];
#pragma unroll
    for (int i = 0; i < 7; ++i) {
      int e = tid + i * 256;        // < 1792 = 56*32
      int row = e >> 5, kc = e & 31;
      LB[row][kc] = XPW[(size_t)row * DINNER + k0 + kc];
    }
    __syncthreads();
    bf16x8 af[2], bfr[2];
    af[0]  = *(const bf16x8*)&LA[wm + fr][fg*8];
    af[1]  = *(const bf16x8*)&LA[wm + 16 + fr][fg*8];
    bfr[0] = *(const bf16x8*)&LB[wn + fr][fg*8];
    bfr[1] = *(const bf16x8*)&LB[wn + 16 + fr][fg*8];
#pragma unroll
    for (int i = 0; i < 2; ++i)
#pragma unroll
      for (int j = 0; j < 2; ++j)
        acc[i][j] = __builtin_amdgcn_mfma_f32_16x16x32_bf16(af[i], bfr[j], acc[i][j], 0, 0, 0);
    __syncthreads();
  }
#pragma unroll
  for (int i = 0; i < 2; ++i)
#pragma unroll
    for (int j = 0; j < 2; ++j)
#pragma unroll
      for (int r = 0; r < 4; ++r) {
        int n = wn + j*16 + fr;
        int tok = wm + i*16 + fg*4 + r;
        if (n < 56) OT[n][tok] = acc[i][j][r];
      }
  __syncthreads();
  for (int e = tid; e < 56 * 16; e += 256) {
    int row = e >> 4, c4 = e & 15;
    float4 v = *(const float4*)&OT[row][c4 * 4];
    *(float4*)&PART[((size_t)(ks*4 + db) * 56 + row) * SEQL + t0 + c4 * 4] = v;
  }
}

// ---------------- x_proj reduce: DTR (fp32) / BCP chunk-interleaved bf16 ----------------
// BCP[db][tb][c][p]: t = c*32+tb; state s: B at p=(s>>2)*8+(s&3), C at +4
__global__ __launch_bounds__(256) void k_xred(const float* __restrict__ PART,
    float* __restrict__ DTR, unsigned short* __restrict__ BCP) {
  const int idx = blockIdx.x * 256 + threadIdx.x;  // over 4*56*SEQL
  const int db = idx / (56 * SEQL);
  const int r  = idx % (56 * SEQL);
  const int n  = r / SEQL;
  const int t  = r % SEQL;
  float s = 0.f;
#pragma unroll
  for (int ks = 0; ks < KSPL; ++ks)
    s += PART[((size_t)(ks*4 + db) * 56 + n) * SEQL + t];
  if (n < DTRANK) {
    DTR[((size_t)db * DTRANK + n) * SEQL + t] = s;
  } else {
    int m = n - DTRANK;          // 0..31; B: m<16 (state m), C: m>=16 (state m-16)
    int st = (m < 16) ? m : (m - 16);
    int p = (st >> 2) * 8 + (st & 3) + ((m < 16) ? 0 : 4);
    int c = t >> 5, tb = t & 31;
    BCP[(size_t)db * BCPD + ((size_t)tb * 64 + c) * 32 + p] = f2bf(s);
  }
}

// ---------------- dt_proj + softplus -> delta (bf16) ----------------
__global__ __launch_bounds__(256) void k_dtproj(const float* __restrict__ DTR,
    const float* __restrict__ WDT, const float* __restrict__ BDT,
    unsigned short* __restrict__ DELTA) {
  __shared__ float S[DTRANK][256];
  const int t0 = blockIdx.x * 256;
  const int d0 = blockIdx.y * 8;
  const int db = blockIdx.z;  // dir*NBATCH + b
  const int tid = threadIdx.x;
  const float* src = DTR + (size_t)(db * DTRANK) * SEQL;
#pragma unroll
  for (int r = 0; r < DTRANK; ++r) S[r][tid] = src[(size_t)r * SEQL + t0 + tid];
  __syncthreads();
#pragma unroll
  for (int i = 0; i < 8; ++i) {
    int d = d0 + i;
    float s = BDT[d];
#pragma unroll
    for (int r = 0; r < DTRANK; ++r) s = fmaf(WDT[d*DTRANK + r], S[r][tid], s);
    float sp = fmaxf(s, 0.f) + log1pf(__expf(-fabsf(s)));
    DELTA[(size_t)(db * DINNER + d) * SEQL + t0 + tid] = f2bf(sp);
  }
}

// ---------------- fused selective scan: packed-f32 (v_pk_fma) inner loop ----------------
// One block = one channel, 64 chunks x 32 steps. BCP bf16 chunk-interleaved;
// A pre-scaled by log2(e) so dA = v_exp directly; state math in float2 pairs.
__global__ __launch_bounds__(256) void k_scanf(const unsigned short* __restrict__ DELTA,
    const unsigned short* __restrict__ XC, const unsigned short* __restrict__ BCP,
    const float* __restrict__ Alog, const float* __restrict__ Ablog,
    const float* __restrict__ Dp, unsigned short* __restrict__ Y) {
  __shared__ __align__(16) unsigned short sd[NCHUNK * CHSTR];  // delta (bf16)
  __shared__ __align__(16) unsigned short sx[NCHUNK * CHSTR];  // conv+silu x (bf16)
  __shared__ __align__(16) unsigned short sy[NCHUNK * CHSTR];  // ungated y staging
  __shared__ float sHL[NCHUNK][16];   // local h_end -> (in-place) h_start
  __shared__ float sDS[NCHUNK];
  const int tid = threadIdx.x;
  const int ch = blockIdx.x;          // 0..NCH-1
  const int db = ch / DINNER;         // dir*2 + b
  const int d  = ch % DINNER;
  const int dir = db >> 1;
  const unsigned short* gd = DELTA + (size_t)(db * DINNER + d) * SEQL;
  const unsigned short* gx = XC    + (size_t)(db * DINNER + d) * SEQL;
  const unsigned short* bcq = BCP + (size_t)db * BCPD;
  {
    int e = tid * 8;
    int r = e >> 5, cl = e & 31;
    *(u16x8*)&sd[r * CHSTR + cl] = *(const u16x8*)&gd[e];
    *(u16x8*)&sx[r * CHSTR + cl] = *(const u16x8*)&gx[e];
  }
  const int lk = tid & 3;            // state-quad lane
  const int cq = tid >> 2;           // chunk 0..63
  const float* Ap = (dir ? Ablog : Alog) + (size_t)d * NSTATE + 4 * lk;
  f32x2 Av01, Av23;                  // -exp(A_log) * log2(e), packed
  Av01.x = -__expf(Ap[0]) * LOG2E;  Av01.y = -__expf(Ap[1]) * LOG2E;
  Av23.x = -__expf(Ap[2]) * LOG2E;  Av23.y = -__expf(Ap[3]) * LOG2E;
  __syncthreads();
  // ---- pass 1: local scan, h0 = 0 (B-only ushort4 loads) ----
  {
    f32x2 h01 = {0.f, 0.f}, h23 = {0.f, 0.f};
    float dsum = 0.f;
#pragma unroll 2
    for (int tb4 = 0; tb4 < CHUNK; tb4 += 4) {
      const int base = cq * CHSTR + tb4;
      ushort4 dl4 = *(const ushort4*)&sd[base];   // quad-broadcast 8B
      ushort4 xl4 = *(const ushort4*)&sx[base];
      float dl[4] = {bf2f(dl4.x), bf2f(dl4.y), bf2f(dl4.z), bf2f(dl4.w)};
      float xl[4] = {bf2f(xl4.x), bf2f(xl4.y), bf2f(xl4.z), bf2f(xl4.w)};
      dsum += dl[0] + dl[1] + dl[2] + dl[3];
#pragma unroll
      for (int k = 0; k < 4; ++k) {
        float u = dl[k] * xl[k];
        ushort4 b4 = *(const ushort4*)&bcq[((size_t)(tb4 + k) * 64 + cq) * 32 + lk * 8];
        f32x2 dl2 = {dl[k], dl[k]};
        f32x2 t01 = dl2 * Av01, t23 = dl2 * Av23;
        f32x2 dA01, dA23;
        dA01.x = __builtin_amdgcn_exp2f(t01.x); dA01.y = __builtin_amdgcn_exp2f(t01.y);
        dA23.x = __builtin_amdgcn_exp2f(t23.x); dA23.y = __builtin_amdgcn_exp2f(t23.y);
        f32x2 u2 = {u, u};
        f32x2 b01 = {bf2f(b4.x), bf2f(b4.y)};
        f32x2 b23 = {bf2f(b4.z), bf2f(b4.w)};
        h01 = __builtin_elementwise_fma(dA01, h01, u2 * b01);
        h23 = __builtin_elementwise_fma(dA23, h23, u2 * b23);
      }
    }
    if (lk == 0) sDS[cq] = dsum;
    float4 hv = {h01.x, h01.y, h23.x, h23.y};
    *(float4*)&sHL[cq][4 * lk] = hv;
  }
  __syncthreads();
  // ---- fixup (in place): sHL[c] becomes h_start for chunk c ----
  if (tid < NSTATE) {
    const int n = tid;
    const float Aval = -__expf((dir ? Ablog : Alog)[(size_t)d * NSTATE + n]) * LOG2E;
    float hh = 0.f;
#pragma unroll
    for (int c2 = 0; c2 < NCHUNK; ++c2) {
      float tmp = sHL[c2][n];
      sHL[c2][n] = hh;
      hh = fmaf(__builtin_amdgcn_exp2f(sDS[c2] * Aval), hh, tmp);
    }
  }
  __syncthreads();
  // ---- pass 2: recompute with true h_start, emit UNGATED y into sy ----
  {
    const float Dd = Dp[d];
    float4 h0v = *(const float4*)&sHL[cq][4 * lk];
    f32x2 h01 = {h0v.x, h0v.y}, h23 = {h0v.z, h0v.w};
#pragma unroll 2
    for (int tb4 = 0; tb4 < CHUNK; tb4 += 4) {
      const int base = cq * CHSTR + tb4;
      ushort4 dl4 = *(const ushort4*)&sd[base];
      ushort4 xl4 = *(const ushort4*)&sx[base];
      float dl[4] = {bf2f(dl4.x), bf2f(dl4.y), bf2f(dl4.z), bf2f(dl4.w)};
      float xl[4] = {bf2f(xl4.x), bf2f(xl4.y), bf2f(xl4.z), bf2f(xl4.w)};
      float pp[4];
#pragma unroll
      for (int k = 0; k < 4; ++k) {
        float u = dl[k] * xl[k];
        u16x8 v = *(const u16x8*)&bcq[((size_t)(tb4 + k) * 64 + cq) * 32 + lk * 8];
        f32x2 dl2 = {dl[k], dl[k]};
        f32x2 t01 = dl2 * Av01, t23 = dl2 * Av23;
        f32x2 dA01, dA23;
        dA01.x = __builtin_amdgcn_exp2f(t01.x); dA01.y = __builtin_amdgcn_exp2f(t01.y);
        dA23.x = __builtin_amdgcn_exp2f(t23.x); dA23.y = __builtin_amdgcn_exp2f(t23.y);
        f32x2 u2 = {u, u};
        f32x2 b01 = {bf2f(v[0]), bf2f(v[1])};
        f32x2 b23 = {bf2f(v[2]), bf2f(v[3])};
        f32x2 c01 = {bf2f(v[4]), bf2f(v[5])};
        f32x2 c23 = {bf2f(v[6]), bf2f(v[7])};
        h01 = __builtin_elementwise_fma(dA01, h01, u2 * b01);
        h23 = __builtin_elementwise_fma(dA23, h23, u2 * b23);
        f32x2 pyv = __builtin_elementwise_fma(h23, c23, h01 * c01);
        pp[k] = pyv.x + pyv.y;
      }
      const int i0 = lk & 1;
      float u0 = __shfl_xor(pp[i0 ^ 1], 1, 4);
      float u1 = __shfl_xor(pp[(i0 ^ 1) + 2], 1, 4);
      float s0 = pp[i0] + u0;
      float s1 = pp[i0 + 2] + u1;
      float send = (lk & 2) ? s0 : s1;
      float v2 = __shfl_xor(send, 2, 4);
      float keep = (lk & 2) ? s1 : s0;
      float ysum = keep + v2;
      float yv = fmaf(xl[lk], Dd, ysum);
      sy[base + lk] = f2bf(yv);
    }
  }
  __syncthreads();
  unsigned short* gy = Y + (size_t)(db * DINNER + d) * SEQL;
  {
    int e = tid * 8;
    int r = e >> 5, cl = e & 31;
    *(u16x8*)&gy[e] = *(const u16x8*)&sy[r * CHSTR + cl];
  }
}

// ---------------- out_proj (bf16 MFMA, 64x64 tile) + residual; gates y during staging ----------------
__global__ __launch_bounds__(256) void k_outproj(const unsigned short* __restrict__ Y,
    const unsigned short* __restrict__ ZS, const unsigned short* __restrict__ WB,
    const float* __restrict__ X, float* __restrict__ OUT) {
  __shared__ unsigned short LA[64][40];   // [tok][k] (transposed + gated stage)
  __shared__ unsigned short LB[64][40];   // [o][k]
  const unsigned short* WO = WB + WOFF_WO;
  const int m0 = blockIdx.x * 64;         // token tile
  const int n0 = blockIdx.y * 64;         // output-dim tile
  const int tid = threadIdx.x, lane = tid & 63, w = tid >> 6;
  const int wm = (w >> 1) * 32, wn = (w & 1) * 32;
  const int fr = lane & 15, fg = lane >> 4;
  const int b = m0 >> 11, lb = m0 & (SEQL - 1);
  const unsigned short* y0 = Y + (size_t)b * DINNER * SEQL;                 // fwd, natural
  const unsigned short* y1 = Y + (size_t)(NBATCH + b) * DINNER * SEQL;      // bwd, scan frame
  const unsigned short* zsb = ZS + (size_t)b * DINNER * SEQL;
  const int kk = tid >> 3, tg = (tid & 7) * 8;   // A staging: 32 k x 8 tok-groups
  const int srow = tid >> 2, skg = (tid & 3) * 8; // B staging
  f32x4 acc[2][2] = {};
  for (int k0 = 0; k0 < DINNER; k0 += 32) {
    const unsigned short* p0 = y0  + (size_t)(k0 + kk) * SEQL + lb + tg;
    const unsigned short* p1 = y1  + (size_t)(k0 + kk) * SEQL + (SEQL - 8 - lb - tg);
    const unsigned short* pz = zsb + (size_t)(k0 + kk) * SEQL + lb + tg;
    u16x8 a0 = *(const u16x8*)p0;
    u16x8 a1 = *(const u16x8*)p1;   // reversed block; element i corresponds to tok offset 7-i
    u16x8 az = *(const u16x8*)pz;
#pragma unroll
    for (int i = 0; i < 8; ++i)
      LA[tg + i][kk] = f2bf((bf2f(a0[i]) + bf2f(a1[7 - i])) * bf2f(az[i]));
    u16x8 vb = *(const u16x8*)&WO[(size_t)(n0 + srow) * DINNER + k0 + skg];
    *(u16x8*)&LB[srow][skg] = vb;
    __syncthreads();
    bf16x8 af[2], bfr[2];
    af[0]  = *(const bf16x8*)&LA[wm + fr][fg*8];
    af[1]  = *(const bf16x8*)&LA[wm + 16 + fr][fg*8];
    bfr[0] = *(const bf16x8*)&LB[wn + fr][fg*8];
    bfr[1] = *(const bf16x8*)&LB[wn + 16 + fr][fg*8];
#pragma unroll
    for (int i = 0; i < 2; ++i)
#pragma unroll
      for (int j = 0; j < 2; ++j)
        acc[i][j] = __builtin_amdgcn_mfma_f32_16x16x32_bf16(af[i], bfr[j], acc[i][j], 0, 0, 0);
    __syncthreads();
  }
#pragma unroll
  for (int i = 0; i < 2; ++i)
#pragma unroll
    for (int j = 0; j < 2; ++j)
#pragma unroll
      for (int r = 0; r < 4; ++r) {
        int tok = m0 + wm + i*16 + fg*4 + r;
        int o = n0 + wn + j*16 + fr;
        size_t off = (size_t)tok * DIMX + o;
        OUT[off] = acc[i][j][r] + X[off];
      }
}

extern "C" void kernel_launch(void* const* d_in, const int* in_sizes, int n_in,
                              void* d_out, int out_size, void* d_ws, size_t ws_size,
                              hipStream_t stream) {
  (void)in_sizes; (void)n_in; (void)out_size; (void)ws_size;
  const float* x         = (const float*)d_in[0];
  const float* lin_w     = (const float*)d_in[1];
  const float* lin_b     = (const float*)d_in[2];
  const float* ln_g      = (const float*)d_in[3];
  const float* ln_b      = (const float*)d_in[4];
  const float* in_proj_w = (const float*)d_in[5];
  const float* conv_w    = (const float*)d_in[6];
  const float* conv_b    = (const float*)d_in[7];
  const float* x_proj_w  = (const float*)d_in[8];
  const float* dt_proj_w = (const float*)d_in[9];
  const float* dt_proj_b = (const float*)d_in[10];
  const float* A_log     = (const float*)d_in[11];
  const float* A_b_log   = (const float*)d_in[12];
  const float* Dp        = (const float*)d_in[13];
  const float* out_proj_w= (const float*)d_in[14];
  float* out = (float*)d_out;

  float* ws = (float*)d_ws;
  unsigned short* hb = (unsigned short*)ws; ws += (size_t)NTOK * DIMX / 2;        // bf16 pre-LN H
  unsigned short* h2 = (unsigned short*)ws; ws += (size_t)NTOK * DIMX / 2;        // bf16 post-LN H
  unsigned short* xb = (unsigned short*)ws; ws += (size_t)NTOK * DIMX / 2;        // bf16 X
  unsigned short* xz = (unsigned short*)ws;  ws += (size_t)NBATCH * 2*DINNER * SEQL / 2; // bf16 (z half unused)
  unsigned short* xc  = (unsigned short*)ws;  ws += (size_t)NCH * SEQL / 2;       // bf16
  unsigned short* dlt = (unsigned short*)ws;  ws += (size_t)NCH * SEQL / 2;       // bf16
  unsigned short* zs  = (unsigned short*)ws;  ws += (size_t)NBATCH * DINNER * SEQL / 2; // bf16
  float* dtr  = ws;  ws += (size_t)2 * NBATCH * DTRANK * SEQL;
  unsigned short* bcp = (unsigned short*)ws;  ws += (size_t)4 * BCPD / 2;         // bf16 chunk-interleaved
  unsigned short* wbf = (unsigned short*)ws;  ws += (size_t)(WTOTAL + 512) / 2;   // bf16 weight pool
  float* y01f = ws;  ws += (size_t)NCH * SEQL / 2;            // bf16 Y (+ PART overlay)
  unsigned short* y01 = (unsigned short*)y01f;
  float* PART = y01f; // overlay: KSPL*4*56*SEQL fp32 (1.84M) <= region (3.14M floats); PART dead after k_xred

  k_wcvt<<<(CVT_TOTAL/8 + 255)/256, 256, 0, stream>>>(lin_w, in_proj_w, x_proj_w, out_proj_w, x, wbf, xb);
  k_lin<<<dim3(NTOK/64, DIMX/64), 256, 0, stream>>>(xb, wbf, lin_b, hb);
  k_ln<<<NTOK, 128, 0, stream>>>(hb, ln_g, ln_b, h2);
  k_inproj<<<dim3(NTOK/64, 2*DINNER/128), 256, 0, stream>>>(h2, wbf, xz, zs);
  k_conv<<<(NCH*(SEQL/8))/256, 256, 0, stream>>>(xz, conv_w, conv_b, xc);
  k_xproj<<<dim3(SEQL/64, KSPL, 2*NBATCH), 256, 0, stream>>>(xc, wbf, PART);
  k_xred<<<(2*NBATCH*56*SEQL)/256, 256, 0, stream>>>(PART, dtr, bcp);
  k_dtproj<<<dim3(SEQL/256, DINNER/8, 2*NBATCH), 256, 0, stream>>>(dtr, dt_proj_w, dt_proj_b, dlt);
  k_scanf<<<NCH, 256, 0, stream>>>(dlt, xc, bcp, A_log, A_b_log, Dp, y01);
  k_outproj<<<dim3(NTOK/64, DIMX/64), 256, 0, stream>>>(y01, zs, wbf, x, out);
}